// Round 7
// baseline (1538.435 us; speedup 1.0000x reference)
//
#include <hip/hip_runtime.h>

typedef _Float16 f16;
typedef _Float16 f16x8 __attribute__((ext_vector_type(8)));
typedef float f32x4 __attribute__((ext_vector_type(4)));

__device__ __forceinline__ f32x4 mfma16(f16x8 a, f16x8 b, f32x4 c) {
  return __builtin_amdgcn_mfma_f32_16x16x32_f16(a, b, c, 0, 0, 0);
}
__device__ __forceinline__ float sigm(float x) { return 1.0f / (1.0f + __expf(-x)); }
__device__ __forceinline__ float tanh_fast(float x) { return 1.0f - 2.0f / (__expf(2.0f * x) + 1.0f); }

// device-scope (coherence-point) memory ops: bypass the non-coherent per-XCD L2 path
__device__ __forceinline__ f16x8 load_b128_dev(const void* addr) {
  f16x8 r;
  asm volatile("global_load_dwordx4 %0, %1, off sc0 sc1" : "=v"(r) : "v"(addr) : "memory");
  return r;  // caller MUST s_waitcnt vmcnt(0) before use
}
__device__ __forceinline__ void store_f16_dev(void* addr, f16 v) {
  int iv = (int)__builtin_bit_cast(unsigned short, v);
  asm volatile("global_store_short %0, %1, off sc0 sc1" :: "v"(addr), "v"(iv) : "memory");
}

// ---------------- workspace layout (bytes) ----------------
constexpr size_t OFF_PW0   = 0;            // packed Whh0 frags, 1.5MB
constexpr size_t OFF_PW1   = 1572864;      // packed Whh1 frags, 1.5MB
constexpr size_t OFF_PWI1  = 3145728;      // packed Wih1 frags, 1.5MB
constexpr size_t OFF_WLIN  = 4718592;      // plain f16 [512][512], 0.5MB
constexpr size_t OFF_WP0   = 5242880;      // layer0 Wih frags [96][64][8], 96KB
constexpr size_t OFF_XPAD  = 5341184;      // [128][256][8] f16, 512KB
constexpr size_t OFF_CNT   = 5865472;      // flag0[8][128] + flag1[8][128], 8KB
constexpr size_t OFF_Y0E   = 5873664;      // [129][256][512] f16, 33.8MB (slot0=h0)
constexpr size_t OFF_Y1E   = 39690240;     // [129][256][512] f16, 33.8MB
constexpr size_t OFF_U     = 73506816;     // U f32, 64MB
constexpr size_t OFF_DIAG  = 140615680;    // dsuf/de/du

// ---------------- prep: pack Whh0/Whh1/Wih1 into fragment order ----------------
// frag f = jg*48 + kt*3 + g; [f][lane(64)][8 f16]
// content: row = g*512 + jg*16 + (lane&15); k = kt*32 + (lane>>4)*8
__global__ __launch_bounds__(256) void prep_pack_k(
    const float* __restrict__ Whh0, const float* __restrict__ Whh1,
    const float* __restrict__ Wih1,
    f16* __restrict__ P0, f16* __restrict__ P1, f16* __restrict__ PI1)
{
  int idx = blockIdx.x * 256 + threadIdx.x;          // 0..294911
  int m = idx / 98304;                                // 98304 = 3*2^15: divide, don't mask
  int q = idx - m * 98304;
  const float* W = (m == 0) ? Whh0 : ((m == 1) ? Whh1 : Wih1);
  f16* P = (m == 0) ? P0 : ((m == 1) ? P1 : PI1);
  int lane = q & 63; int f = q >> 6;                 // f 0..1535
  int g = f % 3; int u = f / 3;
  int kt = u & 15; int jg = u >> 4;
  int row = g * 512 + jg * 16 + (lane & 15);
  int k = kt * 32 + (lane >> 4) * 8;
  const float* src = W + (size_t)row * 512 + k;
  f16* dst = P + (size_t)q * 8;
#pragma unroll
  for (int c = 0; c < 8; ++c) dst[c] = (f16)src[c];
}

// ---------------- prep: Wlin, layer0 input-weights, x packing, h0 slots, counters ----------------
__global__ __launch_bounds__(256) void prep_misc_k(
    const float* __restrict__ Wlin, const float* __restrict__ Wih0,
    const float* __restrict__ pn, const float* __restrict__ mn,
    const float* __restrict__ hid,
    f16* __restrict__ WLIN, f16* __restrict__ WP0, f16* __restrict__ XPAD,
    f16* __restrict__ Y0E, f16* __restrict__ Y1E, int* __restrict__ CNT)
{
  int i = blockIdx.x * 256 + threadIdx.x;            // 0..335871
  if (i < 262144) { WLIN[i] = (f16)Wlin[i]; return; }
  i -= 262144;
  if (i < 6144) {                                     // WP0 frags: f = jg*3+g
    int lane = i & 63; int f = i >> 6;
    int g = f % 3; int jg = f / 3;
    int kg = lane >> 4;
    int row = g * 512 + jg * 16 + (lane & 15);
    f16* dst = WP0 + (size_t)i * 8;
#pragma unroll
    for (int c = 0; c < 8; ++c)
      dst[c] = (kg == 0 && c < 6) ? (f16)Wih0[row * 6 + c] : (f16)0.f;
    return;
  }
  i -= 6144;
  if (i < 32768) {                                    // XPAD chunks
    size_t tb = i;
    f16* dst = XPAD + tb * 8;
#pragma unroll
    for (int c = 0; c < 8; ++c) {
      float v = (c < 4) ? pn[tb * 4 + c] : ((c < 6) ? mn[tb * 2 + (c - 4)] : 0.f);
      dst[c] = (f16)v;
    }
    return;
  }
  i -= 32768;
  if (i < 32768) {                                    // h0 slot0 of Y0E/Y1E
    int layer = i >> 14; int c = i & 16383;
    f16* dst = (layer ? Y1E : Y0E) + (size_t)c * 8;
    const float* src = hid + (size_t)layer * 131072 + (size_t)c * 8;
#pragma unroll
    for (int e = 0; e < 8; ++e) dst[e] = (f16)src[e];
    return;
  }
  i -= 32768;
  if (i < 2048) CNT[i] = 0;
}

__device__ __forceinline__ void spin_ge16(int* p) {
  int guard = 0;
  while (__hip_atomic_load(p, __ATOMIC_RELAXED, __HIP_MEMORY_SCOPE_AGENT) < 16) {
    __builtin_amdgcn_s_sleep(2);
    if (++guard > (1 << 20)) break;  // deadlock escape (never hit when co-resident)
  }
}

// ---------------- fused 2-layer GRU pipeline: 256 WGs, 1 WG/CU ----------------
// WGs [0,128): layer 0.  WGs [128,256): layer 1, one step behind.
// Per layer: 8 batch-groups x 16 col-WGs; WG = (batch-32 x j-32), 4 waves (2x2).
// LDS: 96KB Whh slice only. h/y0 A-fragments load straight to VGPRs (device-scope).
// L1 slack-phase: gi(t) = y0(t)@Wih1^T computed BEFORE waiting on own h(t) flag.
__global__ __launch_bounds__(256, 1) void gru_fused_k(
    const f16* __restrict__ PW0, const f16* __restrict__ PW1, const f16* __restrict__ PWI1,
    const f16* __restrict__ WP0, const f16* __restrict__ xpad,
    const float* __restrict__ hidden_in,
    const float* __restrict__ bih0, const float* __restrict__ bhh0,
    const float* __restrict__ bih1, const float* __restrict__ bhh1,
    f16* __restrict__ Y0E, f16* __restrict__ Y1E,
    float* __restrict__ hT_out, int* __restrict__ cnt)
{
  extern __shared__ char smem[];             // 96KB weight slice
  char* WLb = smem;

  const int tid = threadIdx.x, lane = tid & 63, wid = tid >> 6;
  const int colL = lane & 15, kgrp = lane >> 4;
  const bool isL1 = blockIdx.x >= 128;
  const int bid = blockIdx.x & 127;
  const int WGb = bid & 7, WGj = bid >> 3;
  const int bgl = wid & 1, jgl = wid >> 1;
  const int bgG = WGb * 2 + bgl;             // batch-16 group 0..15
  const int jgG = WGj * 2 + jgl;             // j-16 group 0..31
  const int bBase = WGb * 32;
  const int j = jgG * 16 + colL;
  const int arow = bgl * 16 + colL;          // A-frag row within the 32-row tile
  // per-lane element offset of this lane's A-fragment base within one t-slot
  const size_t rowOff = (size_t)(bBase + arow) * 512 + kgrp * 8;

  f16* Yme = isL1 ? Y1E : Y0E;
  int* flag0 = cnt + WGb * 128;
  int* flagMe = flag0 + (isL1 ? 1024 : 0);

  // ---- WG's 96KB Whh slice -> LDS ----
  {
    const f16* wsrc = (isL1 ? PW1 : PW0) + (size_t)WGj * 96 * 512;
#pragma unroll
    for (int c = 0; c < 24; ++c) {
      int cid = tid + 256 * c;
      *(f16x8*)(WLb + (size_t)cid * 16) = *(const f16x8*)(wsrc + (size_t)cid * 8);
    }
  }

  // ---- biases (unified cell form) ----
  const float* bih = isL1 ? bih1 : bih0;
  const float* bhh = isL1 ? bhh1 : bhh0;
  const float bs_r = bih[j] + bhh[j];
  const float bs_z = bih[512 + j] + bhh[512 + j];
  const float b_in = bih[1024 + j];
  const float b_hn = bhh[1024 + j];

  float hreg[4];
#pragma unroll
  for (int i = 0; i < 4; ++i)
    hreg[i] = hidden_in[((size_t)(isL1 ? 1 : 0) * 256 + bgG * 16 + kgrp * 4 + i) * 512 + j];

  // ---- L0 constants: padded input weights + first x fragment ----
  f16x8 WIr[3];
  f16x8 xA;
  if (!isL1) {
#pragma unroll
    for (int g = 0; g < 3; ++g)
      WIr[g] = *(const f16x8*)(WP0 + (((size_t)jgG * 3 + g) * 64 + lane) * 8);
    xA = *(const f16x8*)(xpad + ((size_t)bgG * 16 + colL) * 8);
  }

#pragma unroll 1
  for (int t = 0; t < 128; ++t) {
    f32x4 ar, az, an_, ain;
#pragma unroll
    for (int q = 0; q < 4; ++q) { ar[q] = 0.f; az[q] = 0.f; an_[q] = 0.f; ain[q] = 0.f; }

    // ---- L1 slack phase: y0(t) is ready well before own h(t); do gi now ----
    if (isL1) {
      if (tid == 0) spin_ge16(flag0 + t);
      __syncthreads();
      f16x8 xF[16];
      const f16* xrow = Y0E + (size_t)(t + 1) * 131072 + rowOff;
#pragma unroll
      for (int kt = 0; kt < 16; ++kt)
        xF[kt] = load_b128_dev(xrow + kt * 32);
      asm volatile("s_waitcnt vmcnt(0)" ::: "memory");
      __builtin_amdgcn_sched_barrier(0);
#pragma unroll
      for (int kt = 0; kt < 16; ++kt) {
        const f16* wi = PWI1 + (((size_t)(jgG * 48 + kt * 3)) * 64 + lane) * 8;
        ar  = mfma16(xF[kt], *(const f16x8*)(wi),        ar);
        az  = mfma16(xF[kt], *(const f16x8*)(wi + 512),  az);
        ain = mfma16(xF[kt], *(const f16x8*)(wi + 1024), ain);
      }
    }

    // ---- acquire own h(t) ----
    if (tid == 0 && t > 0) spin_ge16(flagMe + t - 1);
    __syncthreads();                         // (t==0: also covers LDS weight copy)

    // ---- h A-fragments straight to registers ----
    f16x8 hA[16];
    {
      const f16* hrow = Yme + (size_t)t * 131072 + rowOff;
#pragma unroll
      for (int kt = 0; kt < 16; ++kt)
        hA[kt] = load_b128_dev(hrow + kt * 32);
      asm volatile("s_waitcnt vmcnt(0)" ::: "memory");
      __builtin_amdgcn_sched_barrier(0);
    }

    // ---- h-part MFMAs (weights from LDS) ----
#pragma unroll
    for (int kt = 0; kt < 16; ++kt) {
      const char* wb = WLb + (size_t)(jgl * 48 + kt * 3) * 1024 + lane * 16;
      ar  = mfma16(hA[kt], *(const f16x8*)(wb),        ar);
      az  = mfma16(hA[kt], *(const f16x8*)(wb + 1024), az);
      an_ = mfma16(hA[kt], *(const f16x8*)(wb + 2048), an_);
    }
    if (!isL1) {
      ar  = mfma16(xA, WIr[0], ar);
      az  = mfma16(xA, WIr[1], az);
      ain = mfma16(xA, WIr[2], ain);
    }

    // ---- cell update; device-scope store of h(t+1) (= y[t]) ----
    {
      f16* yb = Yme + ((size_t)(t + 1) * 256 + bgG * 16 + kgrp * 4) * 512 + j;
#pragma unroll
      for (int i = 0; i < 4; ++i) {
        float r = sigm(ar[i] + bs_r);
        float z = sigm(az[i] + bs_z);
        float n = tanh_fast(ain[i] + b_in + r * (an_[i] + b_hn));
        float hnew = (1.f - z) * n + z * hreg[i];
        hreg[i] = hnew;
        store_f16_dev(yb + (size_t)i * 512, (f16)hnew);
      }
    }

    // ---- release ----
    asm volatile("s_waitcnt vmcnt(0)" ::: "memory");
    __syncthreads();
    if (tid == 0)
      __hip_atomic_fetch_add(&flagMe[t], 1, __ATOMIC_RELAXED, __HIP_MEMORY_SCOPE_AGENT);

    // ---- L0: prefetch next x fragment (overlaps next spin) ----
    if (!isL1)
      xA = *(const f16x8*)(xpad + ((size_t)((t + 1) & 127) * 256 + bgG * 16 + colL) * 8);
  }

  float* ht = hT_out + (isL1 ? 131072 : 0);
#pragma unroll
  for (int i = 0; i < 4; ++i)
    ht[((size_t)bgG * 16 + kgrp * 4 + i) * 512 + j] = hreg[i];
}

// ---------------- u = y1 @ Wlin^T + b_lin (fp32 out) ----------------
__global__ __launch_bounds__(256, 1) void gemm_u_k(
    const f16* __restrict__ A, const f16* __restrict__ B,
    const float* __restrict__ bias, float* __restrict__ C)
{
  const int lane = threadIdx.x & 63, wd = threadIdx.x >> 6;
  const int colL = lane & 15, kgrp = lane >> 4;
  const int m0 = blockIdx.x * 64;
  const int n0 = wd * 128;
  f32x4 acc[4][8];
#pragma unroll
  for (int a = 0; a < 4; ++a)
#pragma unroll
    for (int n = 0; n < 8; ++n)
#pragma unroll
      for (int q = 0; q < 4; ++q) acc[a][n][q] = 0.f;

  for (int kt = 0; kt < 16; ++kt) {
    f16x8 aF[4];
#pragma unroll
    for (int at = 0; at < 4; ++at)
      aF[at] = *(const f16x8*)(A + ((size_t)(m0 + at * 16 + colL)) * 512 + kt * 32 + kgrp * 8);
#pragma unroll
    for (int nt = 0; nt < 8; ++nt) {
      f16x8 bF = *(const f16x8*)(B + ((size_t)(n0 + nt * 16 + colL)) * 512 + kt * 32 + kgrp * 8);
#pragma unroll
      for (int at = 0; at < 4; ++at)
        acc[at][nt] = mfma16(aF[at], bF, acc[at][nt]);
    }
  }
#pragma unroll
  for (int nt = 0; nt < 8; ++nt) {
    int col = n0 + nt * 16 + colL;
    float bv = bias[col];
#pragma unroll
    for (int at = 0; at < 4; ++at)
#pragma unroll
      for (int i = 0; i < 4; ++i)
        C[((size_t)(m0 + at * 16 + kgrp * 4 + i)) * 512 + col] = acc[at][nt][i] + bv;
  }
}

// ---------------- normalization pass 1 ----------------
__global__ __launch_bounds__(256) void norm1_k(const float* __restrict__ U,
    float* __restrict__ dsuf, float* __restrict__ de, float* __restrict__ du)
{
  int id = blockIdx.x * 4 + (threadIdx.x >> 6);
  int lane = threadIdx.x & 63;
  int k = id >> 8;
  const float* row = U + (size_t)id * 512;
  f32x4 v0 = *(const f32x4*)(row + lane * 8);
  f32x4 v1 = *(const f32x4*)(row + lane * 8 + 4);
  float vals[8] = {v0[0], v0[1], v0[2], v0[3], v1[0], v1[1], v1[2], v1[3]};
  int j0 = lane * 8;
  float s = 0.f;
#pragma unroll
  for (int q = 0; q < 8; ++q) {
    float v = ((j0 + q) >= 4 * k) ? vals[q] : 0.f;
    s += v * v;
  }
#pragma unroll
  for (int off = 1; off < 64; off <<= 1) s += __shfl_xor(s, off);
  if (lane == (k >> 1)) {
    int o = (k & 1) * 4;
    float e = vals[o] * vals[o] + vals[o + 1] * vals[o + 1] +
              vals[o + 2] * vals[o + 2] + vals[o + 3] * vals[o + 3];
    de[id] = e; dsuf[id] = s;
    f32x4 d = {vals[o], vals[o + 1], vals[o + 2], vals[o + 3]};
    *(f32x4*)(du + (size_t)id * 4) = d;
  }
}

// ---------------- normalization pass 2 ----------------
__global__ __launch_bounds__(256) void norm2_k(const float* __restrict__ dsuf,
    const float* __restrict__ de, const float* __restrict__ du, float* __restrict__ out)
{
  int b = threadIdx.x;
  float L = 128.f;
  for (int kc = 0; kc < 8; ++kc) {
    float ss[16], ee[16]; f32x4 dd[16];
#pragma unroll
    for (int q = 0; q < 16; ++q) {
      int id = (kc * 16 + q) * 256 + b;
      ss[q] = dsuf[id]; ee[q] = de[id];
      dd[q] = *(const f32x4*)(du + (size_t)id * 4);
    }
#pragma unroll
    for (int q = 0; q < 16; ++q) {
      int id = (kc * 16 + q) * 256 + b;
      float sc = sqrtf(L / ss[q]);
      f32x4 o = dd[q];
      o[0] *= sc; o[1] *= sc; o[2] *= sc; o[3] *= sc;
      *(f32x4*)(out + (size_t)id * 4) = o;
      L *= (1.f - ee[q] / ss[q]);
    }
  }
}

// ---------------- launch ----------------
extern "C" void kernel_launch(void* const* d_in, const int* in_sizes, int n_in,
                              void* d_out, int out_size, void* d_ws, size_t ws_size,
                              hipStream_t stream) {
  (void)in_sizes; (void)n_in; (void)out_size; (void)ws_size;
  const float* pn   = (const float*)d_in[0];
  const float* mn   = (const float*)d_in[1];
  const float* hid  = (const float*)d_in[2];
  const float* Wih0 = (const float*)d_in[3];
  const float* Whh0 = (const float*)d_in[4];
  const float* bih0 = (const float*)d_in[5];
  const float* bhh0 = (const float*)d_in[6];
  const float* Wih1 = (const float*)d_in[7];
  const float* Whh1 = (const float*)d_in[8];
  const float* bih1 = (const float*)d_in[9];
  const float* bhh1 = (const float*)d_in[10];
  const float* Wlin = (const float*)d_in[11];
  const float* blin = (const float*)d_in[12];
  float* out = (float*)d_out;
  char* ws = (char*)d_ws;

  f16* PW0  = (f16*)(ws + OFF_PW0);
  f16* PW1  = (f16*)(ws + OFF_PW1);
  f16* PWI1 = (f16*)(ws + OFF_PWI1);
  f16* WLIN = (f16*)(ws + OFF_WLIN);
  f16* WP0  = (f16*)(ws + OFF_WP0);
  f16* XPAD = (f16*)(ws + OFF_XPAD);
  int* CNT  = (int*)(ws + OFF_CNT);
  f16* Y0E  = (f16*)(ws + OFF_Y0E);
  f16* Y1E  = (f16*)(ws + OFF_Y1E);
  float* U  = (float*)(ws + OFF_U);
  float* DSUF = (float*)(ws + OFF_DIAG);
  float* DE   = (float*)(ws + OFF_DIAG + 131072);
  float* DU   = (float*)(ws + OFF_DIAG + 262144);

  hipFuncSetAttribute(reinterpret_cast<const void*>(gru_fused_k),
                      hipFuncAttributeMaxDynamicSharedMemorySize, 98304);

  prep_pack_k<<<1152, 256, 0, stream>>>(Whh0, Whh1, Wih1, PW0, PW1, PWI1);
  prep_misc_k<<<1312, 256, 0, stream>>>(Wlin, Wih0, pn, mn, hid,
                                        WLIN, WP0, XPAD, Y0E, Y1E, CNT);
  gru_fused_k<<<256, 256, 98304, stream>>>(PW0, PW1, PWI1, WP0, XPAD, hid,
                                           bih0, bhh0, bih1, bhh1,
                                           Y0E, Y1E, out + 131072, CNT);
  gemm_u_k<<<512, 256, 0, stream>>>(Y1E + 131072, WLIN, blin, U);
  norm1_k<<<8192, 256, 0, stream>>>(U, DSUF, DE, DU);
  norm2_k<<<1, 256, 0, stream>>>(DSUF, DE, DU, out);
}